// Round 4
// baseline (188.521 us; speedup 1.0000x reference)
//
#include <hip/hip_runtime.h>
#include <hip/hip_bf16.h>

typedef __attribute__((ext_vector_type(8))) short bf16x8;
typedef __attribute__((ext_vector_type(4))) float f32x4;

#define MFMA16(a, b, c) __builtin_amdgcn_mfma_f32_16x16x32_bf16(a, b, c, 0, 0, 0)

static constexpr int kH = 12;
static constexpr int kN = 1024;
static constexpr int kD = 64;
static constexpr int kBH = 96;
static constexpr int kND = kN * kD;            // 65536 per head
static constexpr float kScale = 0.125f;
static constexpr float kEps = 1e-6f;
static constexpr long kTensorElems = (long)kBH * kND;     // 6291456
static constexpr long kWsNeeded = 2 * kTensorElems * 2;   // K + Vt bf16

// ---------- bf16 helpers ----------
__device__ __forceinline__ unsigned bfbits(float x) {
    union { __hip_bfloat16 h; unsigned short u; } c;
    c.h = __float2bfloat16(x);
    return (unsigned)c.u;
}
__device__ __forceinline__ unsigned pack2_rne(float a, float b) {
    return bfbits(a) | (bfbits(b) << 16);
}
// round-half-up pack (operands >= 0 post-ReLU)
__device__ __forceinline__ unsigned pack2_rhu(float lo, float hi) {
    unsigned a = __builtin_bit_cast(unsigned, lo) + 0x8000u;
    unsigned b = __builtin_bit_cast(unsigned, hi) + 0x8000u;
    return __builtin_amdgcn_perm(b, a, 0x07060302u);
}
__device__ __forceinline__ void gl_lds16(const void* g, void* l) {
    __builtin_amdgcn_global_load_lds(
        (const __attribute__((address_space(1))) void*)g,
        (__attribute__((address_space(3))) void*)l, 16, 0, 0);
}

// ---------- prepass: K fp32->bf16 cast + V fp32 [n][d] -> Vt bf16 [d][n] ----------
__global__ __launch_bounds__(256, 2) void prep(
    const float* __restrict__ k, const float* __restrict__ v,
    unsigned* __restrict__ kbf, unsigned* __restrict__ vtb)
{
    static constexpr int TS = 68;
    __shared__ float T32[64 * TS];
    const int bid = blockIdx.x;                   // 1536 = 96 bh * 16 nt
    const int bh = bid >> 4, nt = bid & 15;
    const int t = threadIdx.x;

    const float* kp = k + (long)bh * kND + (long)nt * 64 * kD;
    unsigned* ko = kbf + ((long)bh * kND + (long)nt * 64 * kD) / 2;
#pragma unroll
    for (int r = 0; r < 4; ++r) {
        const int f4 = t + 256 * r;
        const float4 f = ((const float4*)kp)[f4];
        uint2 u;
        u.x = pack2_rne(f.x, f.y);
        u.y = pack2_rne(f.z, f.w);
        *(uint2*)&ko[f4 * 2] = u;
    }

    const float* vp = v + (long)bh * kND + (long)nt * 64 * kD;
#pragma unroll
    for (int r = 0; r < 4; ++r) {
        const int f4 = t + 256 * r;
        const int n = f4 >> 4, d4 = f4 & 15;
        const float4 f = *(const float4*)(vp + (long)n * kD + 4 * d4);
        *(float4*)&T32[n * TS + 4 * d4] = f;
    }
    __syncthreads();
    const int d = t >> 2, c = t & 3;
    unsigned u[8];
#pragma unroll
    for (int j = 0; j < 8; ++j) {
        const int key = c * 16 + 2 * j;
        u[j] = pack2_rne(T32[key * TS + d], T32[(key + 1) * TS + d]);
    }
    unsigned* dst = vtb + (long)bh * (kND / 2) + (long)d * (kN / 2) + nt * 32 + c * 8;
    *(uint4*)(dst)     = *(uint4*)&u[0];
    *(uint4*)(dst + 4) = *(uint4*)&u[4];
}

// ---------- main attention kernel ----------
// grid 1536: 64 q-rows per block. 4 waves = 2 key-slices (ks) x 2 q-slices (qs);
// each wave owns 32 keys x 32 q per 64-key tile. 2-way O/denom reduce at end.
__global__ __launch_bounds__(256, 5) void l2q_main(
    const float* __restrict__ q,
    const unsigned short* __restrict__ kbf, const unsigned short* __restrict__ vtbf,
    const float* __restrict__ alpha, const float* __restrict__ beta, const float* __restrict__ gamma,
    float* __restrict__ out)
{
    // SMEM: Ks[2048] | Vs[2048] | P 4*640 (rows of 20 uints, pad vs conflicts) = 26624 B
    __shared__ __align__(16) unsigned SMEM[6656];
    unsigned* Ks = SMEM;            // 64 key-rows x 32 uints (64 bf16), 8-granule xor-swizzle
    unsigned* Vs = SMEM + 2048;     // 64 d-rows  x 32 uints (keys), same swizzle
    unsigned* Pu = SMEM + 4096;

    const int bid  = blockIdx.x;
    const int xcd  = bid & 7;                  // XCD head-pinning (R3 win: FETCH -4x)
    const int sIdx = bid >> 3;                 // 0..191
    const int bh   = xcd * 12 + (sIdx % 12);
    const int qt   = sIdx / 12;                // 0..15 (64-row q-tiles)
    const int h    = bh % kH;
    const int t    = threadIdx.x;
    const int wave = t >> 6;
    const int lane = t & 63;
    const int quad = lane >> 4;
    const int l15  = lane & 15;
    const int ks   = wave & 1;                 // key-slice
    const int qs   = wave >> 1;                // q-slice

    const float al = alpha[h] * (kScale * kScale);
    const float be = beta[h] * kScale;
    const float ga = gamma[h];

    const float* qp = q + (long)bh * kND;
    const unsigned short* kp = kbf + (long)bh * kND;
    const unsigned short* vp = vtbf + (long)bh * kND;   // [d][n]

    // Q fragments (B-operand: n=q=l15, k=d=quad*8+j): 32 q-rows -> nb2 x kc2
    bf16x8 qa[2][2];
#pragma unroll
    for (int nb = 0; nb < 2; ++nb) {
        const int row = qt * 64 + qs * 32 + nb * 16 + l15;
#pragma unroll
        for (int kc = 0; kc < 2; ++kc) {
            const float* src = qp + (long)row * kD + kc * 32 + quad * 8;
            const float4 f0 = *(const float4*)(src);
            const float4 f1 = *(const float4*)(src + 4);
            uint4 u;
            u.x = pack2_rne(f0.x, f0.y);
            u.y = pack2_rne(f0.z, f0.w);
            u.z = pack2_rne(f1.x, f1.y);
            u.w = pack2_rne(f1.z, f1.w);
            qa[nb][kc] = __builtin_bit_cast(bf16x8, u);
        }
    }

    f32x4 oacc[2][4];
#pragma unroll
    for (int qb = 0; qb < 2; ++qb)
#pragma unroll
        for (int db = 0; db < 4; ++db)
            oacc[qb][db] = (f32x4){0.f, 0.f, 0.f, 0.f};
    float dsum[2] = {0.f, 0.f};

    unsigned* Pw = Pu + wave * 640;            // 32 rows x 20 uints
    const int srow8 = lane >> 3;               // staging row-in-chunk
    const int g8    = lane & 7;                // staging granule slot
    const int sw3   = l15 & 3;

    for (int tile = 0; tile < 16; ++tile) {
        __syncthreads();                       // prev tile's K/V reads done
        const int k0 = tile * 64;
        // ---- stage K + Vt (single buffer, 8KB each; 4 gl_lds16 per wave) ----
#pragma unroll
        for (int c = 0; c < 2; ++c) {
            const int r = (c * 4 + wave) * 8 + srow8;           // 0..63
            gl_lds16(kp + (long)(k0 + r) * kD + (g8 ^ (r & 7)) * 8, &Ks[(c * 4 + wave) * 256]);
            gl_lds16(vp + (long)r * kN + k0 + (g8 ^ (r & 7)) * 8, &Vs[(c * 4 + wave) * 256]);
        }
        __syncthreads();                       // staging visible (drains vmcnt)

        // ---- S^T = K Q^T : wave's 32 keys x 32 q ----
        f32x4 st[2][2];                        // [kb][nb]
#pragma unroll
        for (int kb = 0; kb < 2; ++kb)
#pragma unroll
            for (int nb = 0; nb < 2; ++nb)
                st[kb][nb] = (f32x4){0.f, 0.f, 0.f, 0.f};
#pragma unroll
        for (int kb = 0; kb < 2; ++kb) {
            const int krow = ks * 32 + kb * 16 + l15;
            const int sw = krow & 7;
            const int rbase = krow * 32;
            bf16x8 kf0 = *(const bf16x8*)&Ks[rbase + ((quad ^ sw) << 2)];
            bf16x8 kf1 = *(const bf16x8*)&Ks[rbase + (((4 + quad) ^ sw) << 2)];
#pragma unroll
            for (int nb = 0; nb < 2; ++nb) {
                st[kb][nb] = MFMA16(kf0, qa[nb][0], st[kb][nb]);
                st[kb][nb] = MFMA16(kf1, qa[nb][1], st[kb][nb]);
            }
        }

        // ---- poly + ReLU + denom + pack P (rows=local q, cols=local key) ----
#pragma unroll
        for (int nb = 0; nb < 2; ++nb) {
            const int pbase = (nb * 16 + l15) * 20;
            float dadd = 0.f;
#pragma unroll
            for (int kb = 0; kb < 2; ++kb) {
                f32x4 sv = st[kb][nb];
                f32x4 w = sv * al + be;
                w = w * sv + ga;
                w[0] = fmaxf(w[0], 0.f); w[1] = fmaxf(w[1], 0.f);
                w[2] = fmaxf(w[2], 0.f); w[3] = fmaxf(w[3], 0.f);
                dadd += (w[0] + w[1]) + (w[2] + w[3]);
                uint2 pk2;
                pk2.x = pack2_rhu(w[0], w[1]);
                pk2.y = pack2_rhu(w[2], w[3]);
                const int g = kb * 2 + (quad >> 1);
                *(uint2*)&Pw[pbase + ((g ^ sw3) << 2) + (quad & 1) * 2] = pk2;
            }
            dsum[nb] += dadd;
        }
        __asm__ __volatile__("" ::: "memory");

        // ---- O += P V over wave's 32 keys (K=32 per MFMA) ----
        bf16x8 pf[2];
        pf[0] = *(const bf16x8*)&Pw[(l15)      * 20 + ((quad ^ sw3) << 2)];
        pf[1] = *(const bf16x8*)&Pw[(16 + l15) * 20 + ((quad ^ sw3) << 2)];
#pragma unroll
        for (int db = 0; db < 4; ++db) {
            const int vrow = db * 16 + l15;
            bf16x8 vf = *(const bf16x8*)&Vs[vrow * 32 + (((ks * 4 + quad) ^ (vrow & 7)) << 2)];
            oacc[0][db] = MFMA16(pf[0], vf, oacc[0][db]);
            oacc[1][db] = MFMA16(pf[1], vf, oacc[1][db]);
        }
        __asm__ __volatile__("" ::: "memory");
    }

    // ---- cross-wave (ks) reduction of denominator and O ----
    // Dred in P area (P dead after barrier): [qs][ql 0..31][ks] floats
    float* DredF = (float*)Pu;
    // O partial from ks=1 waves, per qs: 32 q x 64 d fp32 (8KB) in Ks/Vs area
    float* O1 = (float*)(SMEM + qs * 2048);

    float dred[2];
#pragma unroll
    for (int nb = 0; nb < 2; ++nb) {
        float d = dsum[nb];
        d += __shfl_xor(d, 16);
        d += __shfl_xor(d, 32);
        dred[nb] = d;                          // wave's 32-key partial for q = nb*16+l15
    }
    __syncthreads();                           // all tiles done; LDS reusable
    if (quad == 0) {
#pragma unroll
        for (int nb = 0; nb < 2; ++nb)
            DredF[(qs * 32 + nb * 16 + l15) * 2 + ks] = dred[nb];
    }
    if (ks == 1) {
#pragma unroll
        for (int qb = 0; qb < 2; ++qb)
#pragma unroll
            for (int db = 0; db < 4; ++db)
#pragma unroll
                for (int i = 0; i < 4; ++i)
                    O1[(qb * 16 + quad * 4 + i) * 64 + db * 16 + l15] = oacc[qb][db][i];
    }
    __syncthreads();
    if (ks == 0) {
        const long obase = (long)bh * kND;
#pragma unroll
        for (int qb = 0; qb < 2; ++qb)
#pragma unroll
            for (int i = 0; i < 4; ++i) {
                const int ql = qb * 16 + quad * 4 + i;
                const float dd = DredF[(qs * 32 + ql) * 2 + 0] + DredF[(qs * 32 + ql) * 2 + 1];
                const float inv = 1.0f / (dd + kEps);
                const int row = qt * 64 + qs * 32 + ql;
#pragma unroll
                for (int db = 0; db < 4; ++db) {
                    const float val = (oacc[qb][db][i] + O1[ql * 64 + db * 16 + l15]) * inv;
                    out[obase + (long)row * kD + db * 16 + l15] = val;
                }
            }
    }
}

// ---------- fallback (fp32 direct) for small ws ----------
static constexpr int KSU = 36;
static constexpr int VSU = 36;
static constexpr int PSU = 36;

__global__ __launch_bounds__(256, 3) void l2q_attn_fb(
    const float* __restrict__ q, const float* __restrict__ k, const float* __restrict__ v,
    const float* __restrict__ alpha, const float* __restrict__ beta, const float* __restrict__ gamma,
    float* __restrict__ out)
{
    __shared__ __align__(16) unsigned KsU[64 * KSU];
    __shared__ __align__(16) unsigned VtU[64 * VSU];
    __shared__ __align__(16) unsigned PU[128 * PSU];

    const int bid  = blockIdx.x;
    const int bh   = bid >> 3;
    const int qt   = bid & 7;
    const int h    = bh % kH;
    const int t    = threadIdx.x;
    const int wave = t >> 6;
    const int lane = t & 63;
    const int quad = lane >> 4;
    const int l15  = lane & 15;

    const float al = alpha[h], be = beta[h], ga = gamma[h];

    const long base = (long)bh * kN * kD;
    const float* qp = q + base;
    const float* kp = k + base;
    const float* vp = v + base;

    bf16x8 qa[2][2];
#pragma unroll
    for (int rb = 0; rb < 2; ++rb) {
        const int row = qt * 128 + wave * 32 + rb * 16 + l15;
#pragma unroll
        for (int kc = 0; kc < 2; ++kc) {
            const float* src = qp + (long)row * kD + kc * 32 + quad * 8;
            const float4 f0 = *(const float4*)(src);
            const float4 f1 = *(const float4*)(src + 4);
            uint4 u;
            u.x = pack2_rne(f0.x, f0.y);
            u.y = pack2_rne(f0.z, f0.w);
            u.z = pack2_rne(f1.x, f1.y);
            u.w = pack2_rne(f1.z, f1.w);
            qa[rb][kc] = __builtin_bit_cast(bf16x8, u);
        }
    }

    f32x4 oacc[2][4];
#pragma unroll
    for (int rb = 0; rb < 2; ++rb)
#pragma unroll
        for (int db = 0; db < 4; ++db)
            oacc[rb][db] = (f32x4){0.f, 0.f, 0.f, 0.f};

    float dsum[2][4] = {{0.f, 0.f, 0.f, 0.f}, {0.f, 0.f, 0.f, 0.f}};
    unsigned* Pw = &PU[wave * 32 * PSU];

    for (int tile = 0; tile < 16; ++tile) {
        __syncthreads();
        const int k0 = tile * 64;
#pragma unroll
        for (int r = 0; r < 4; ++r) {
            const int f4 = t + 256 * r;
            const int n = f4 >> 4, d4 = f4 & 15;
            const float4 kg = *(const float4*)(kp + (long)(k0 + n) * kD + 4 * d4);
            uint2 pk;
            pk.x = pack2_rne(kg.x, kg.y);
            pk.y = pack2_rne(kg.z, kg.w);
            *(uint2*)&KsU[n * KSU + 2 * d4] = pk;
        }
#pragma unroll
        for (int r = 0; r < 2; ++r) {
            const int u = t + 256 * r;
            const int key2 = u & 31, d4 = u >> 5;
            const float* s0 = vp + (long)(k0 + 2 * key2) * kD + 4 * d4;
            const float4 va = *(const float4*)(s0);
            const float4 vb = *(const float4*)(s0 + kD);
            VtU[(4 * d4 + 0) * VSU + key2] = pack2_rne(va.x, vb.x);
            VtU[(4 * d4 + 1) * VSU + key2] = pack2_rne(va.y, vb.y);
            VtU[(4 * d4 + 2) * VSU + key2] = pack2_rne(va.z, vb.z);
            VtU[(4 * d4 + 3) * VSU + key2] = pack2_rne(va.w, vb.w);
        }
        __syncthreads();

        f32x4 s[2][4];
#pragma unroll
        for (int rb = 0; rb < 2; ++rb)
#pragma unroll
            for (int nb = 0; nb < 4; ++nb)
                s[rb][nb] = (f32x4){0.f, 0.f, 0.f, 0.f};
#pragma unroll
        for (int nb = 0; nb < 4; ++nb) {
            bf16x8 kb0 = *(const bf16x8*)&KsU[(nb * 16 + l15) * KSU + 4 * quad];
            bf16x8 kb1 = *(const bf16x8*)&KsU[(nb * 16 + l15) * KSU + 16 + 4 * quad];
#pragma unroll
            for (int rb = 0; rb < 2; ++rb) {
                s[rb][nb] = MFMA16(qa[rb][0], kb0, s[rb][nb]);
                s[rb][nb] = MFMA16(qa[rb][1], kb1, s[rb][nb]);
            }
        }

        const bool ev = (lane & 1) == 0;
#pragma unroll
        for (int rb = 0; rb < 2; ++rb) {
#pragma unroll
            for (int nb = 0; nb < 4; ++nb) {
                float w0, w1, w2, w3;
                {
                    float l0 = s[rb][nb][0] * kScale;
                    float l1 = s[rb][nb][1] * kScale;
                    float l2 = s[rb][nb][2] * kScale;
                    float l3 = s[rb][nb][3] * kScale;
                    w0 = fmaxf(fmaf(fmaf(al, l0, be), l0, ga), 0.f);
                    w1 = fmaxf(fmaf(fmaf(al, l1, be), l1, ga), 0.f);
                    w2 = fmaxf(fmaf(fmaf(al, l2, be), l2, ga), 0.f);
                    w3 = fmaxf(fmaf(fmaf(al, l3, be), l3, ga), 0.f);
                }
                dsum[rb][0] += w0; dsum[rb][1] += w1;
                dsum[rb][2] += w2; dsum[rb][3] += w3;

                const float o0 = __shfl_xor(w0, 1);
                const float o1 = __shfl_xor(w1, 1);
                const float o2 = __shfl_xor(w2, 1);
                const float o3 = __shfl_xor(w3, 1);
                const unsigned pa = ev ? pack2_rne(w0, o0) : pack2_rne(o2, w2);
                const unsigned pb = ev ? pack2_rne(w1, o1) : pack2_rne(o3, w3);
                const int r0 = ev ? 0 : 2;
                const int cu = (16 * nb + (l15 & ~1)) >> 1;
                const int rowb = rb * 16 + quad * 4 + r0;
                Pw[rowb * PSU + cu] = pa;
                Pw[(rowb + 1) * PSU + cu] = pb;
            }
        }

        bf16x8 pf[2][2];
#pragma unroll
        for (int rb = 0; rb < 2; ++rb)
#pragma unroll
            for (int kc = 0; kc < 2; ++kc)
                pf[rb][kc] = *(const bf16x8*)&Pw[(rb * 16 + l15) * PSU + 16 * kc + 4 * quad];
#pragma unroll
        for (int db = 0; db < 4; ++db) {
            bf16x8 vf0 = *(const bf16x8*)&VtU[(db * 16 + l15) * VSU + 4 * quad];
            bf16x8 vf1 = *(const bf16x8*)&VtU[(db * 16 + l15) * VSU + 16 + 4 * quad];
#pragma unroll
            for (int rb = 0; rb < 2; ++rb) {
                oacc[rb][db] = MFMA16(pf[rb][0], vf0, oacc[rb][db]);
                oacc[rb][db] = MFMA16(pf[rb][1], vf1, oacc[rb][db]);
            }
        }
    }

#pragma unroll
    for (int rb = 0; rb < 2; ++rb)
#pragma unroll
        for (int i = 0; i < 4; ++i) {
            float d = dsum[rb][i];
            d += __shfl_xor(d, 1);
            d += __shfl_xor(d, 2);
            d += __shfl_xor(d, 4);
            d += __shfl_xor(d, 8);
            dsum[rb][i] = 1.0f / (d + kEps);
        }

#pragma unroll
    for (int rb = 0; rb < 2; ++rb)
#pragma unroll
        for (int db = 0; db < 4; ++db)
#pragma unroll
            for (int i = 0; i < 4; ++i) {
                const int row = qt * 128 + wave * 32 + rb * 16 + quad * 4 + i;
                out[base + (long)row * kD + db * 16 + l15] = oacc[rb][db][i] * dsum[rb][i];
            }
}

extern "C" void kernel_launch(void* const* d_in, const int* in_sizes, int n_in,
                              void* d_out, int out_size, void* d_ws, size_t ws_size,
                              hipStream_t stream) {
    const float* q     = (const float*)d_in[0];
    const float* k     = (const float*)d_in[1];
    const float* v     = (const float*)d_in[2];
    const float* alpha = (const float*)d_in[3];
    const float* beta  = (const float*)d_in[4];
    const float* gamma = (const float*)d_in[5];
    float* out = (float*)d_out;

    if (ws_size < (size_t)kWsNeeded) {
        l2q_attn_fb<<<dim3(768), dim3(256), 0, stream>>>(q, k, v, alpha, beta, gamma, out);
        return;
    }

    unsigned* kbf = (unsigned*)d_ws;
    unsigned* vtb = kbf + kTensorElems / 2;

    prep<<<dim3(1536), dim3(256), 0, stream>>>(k, v, kbf, vtb);
    l2q_main<<<dim3(1536), dim3(256), 0, stream>>>(
        q, (const unsigned short*)kbf, (const unsigned short*)vtb,
        alpha, beta, gamma, out);
}

// Round 5
// 150.969 us; speedup vs baseline: 1.2487x; 1.2487x over previous
//
#include <hip/hip_runtime.h>
#include <hip/hip_bf16.h>

typedef __attribute__((ext_vector_type(8))) short bf16x8;
typedef __attribute__((ext_vector_type(4))) float f32x4;
typedef __attribute__((ext_vector_type(16))) float f32x16;

#define MFMA16(a, b, c) __builtin_amdgcn_mfma_f32_16x16x32_bf16(a, b, c, 0, 0, 0)
#define MFMA32(a, b, c) __builtin_amdgcn_mfma_f32_32x32x16_bf16(a, b, c, 0, 0, 0)

static constexpr int kH = 12;
static constexpr int kN = 1024;
static constexpr int kD = 64;
static constexpr int kBH = 96;
static constexpr int kND = kN * kD;            // 65536 per head
static constexpr float kScale = 0.125f;
static constexpr float kEps = 1e-6f;
static constexpr long kTensorElems = (long)kBH * kND;     // 6291456
static constexpr long kWsNeeded = 2 * kTensorElems * 2;   // K + Vt bf16

// ---------- bf16 helpers ----------
__device__ __forceinline__ unsigned bfbits(float x) {
    union { __hip_bfloat16 h; unsigned short u; } c;
    c.h = __float2bfloat16(x);
    return (unsigned)c.u;
}
__device__ __forceinline__ unsigned pack2_rne(float a, float b) {
    return bfbits(a) | (bfbits(b) << 16);
}
// round-half-up pack (operands >= 0 post-ReLU)
__device__ __forceinline__ unsigned pack2_rhu(float lo, float hi) {
    unsigned a = __builtin_bit_cast(unsigned, lo) + 0x8000u;
    unsigned b = __builtin_bit_cast(unsigned, hi) + 0x8000u;
    return __builtin_amdgcn_perm(b, a, 0x07060302u);
}
__device__ __forceinline__ void gl_lds16(const void* g, void* l) {
    __builtin_amdgcn_global_load_lds(
        (const __attribute__((address_space(1))) void*)g,
        (__attribute__((address_space(3))) void*)l, 16, 0, 0);
}

// ---------- prepass: K fp32->bf16 cast + V fp32 [n][d] -> Vt bf16 [d][n] ----------
__global__ __launch_bounds__(256, 2) void prep(
    const float* __restrict__ k, const float* __restrict__ v,
    unsigned* __restrict__ kbf, unsigned* __restrict__ vtb)
{
    static constexpr int TS = 68;
    __shared__ float T32[64 * TS];
    const int bid = blockIdx.x;                   // 1536 = 96 bh * 16 nt
    const int bh = bid >> 4, nt = bid & 15;
    const int t = threadIdx.x;

    const float* kp = k + (long)bh * kND + (long)nt * 64 * kD;
    unsigned* ko = kbf + ((long)bh * kND + (long)nt * 64 * kD) / 2;
#pragma unroll
    for (int r = 0; r < 4; ++r) {
        const int f4 = t + 256 * r;
        const float4 f = ((const float4*)kp)[f4];
        uint2 u;
        u.x = pack2_rne(f.x, f.y);
        u.y = pack2_rne(f.z, f.w);
        *(uint2*)&ko[f4 * 2] = u;
    }

    const float* vp = v + (long)bh * kND + (long)nt * 64 * kD;
#pragma unroll
    for (int r = 0; r < 4; ++r) {
        const int f4 = t + 256 * r;
        const int n = f4 >> 4, d4 = f4 & 15;
        const float4 f = *(const float4*)(vp + (long)n * kD + 4 * d4);
        *(float4*)&T32[n * TS + 4 * d4] = f;
    }
    __syncthreads();
    const int d = t >> 2, c = t & 3;
    unsigned u[8];
#pragma unroll
    for (int j = 0; j < 8; ++j) {
        const int key = c * 16 + 2 * j;
        u[j] = pack2_rne(T32[key * TS + d], T32[(key + 1) * TS + d]);
    }
    unsigned* dst = vtb + (long)bh * (kND / 2) + (long)d * (kN / 2) + nt * 32 + c * 8;
    *(uint4*)(dst)     = *(uint4*)&u[0];
    *(uint4*)(dst + 4) = *(uint4*)&u[4];
}

// ---------- main attention kernel: 32x32x16 MFMA, no P LDS roundtrip ----------
// grid 768: 128 q-rows/block, 4 waves x 32 q-rows. 64-key dbuf tiles, 1 barrier/tile.
__global__ __launch_bounds__(256, 3) void l2q_main(
    const float* __restrict__ q,
    const unsigned short* __restrict__ kbf, const unsigned short* __restrict__ vtbf,
    const float* __restrict__ alpha, const float* __restrict__ beta, const float* __restrict__ gamma,
    float* __restrict__ out)
{
    // K: 64 key-rows x 64 bf16 (32 uints, 8 granules/row, xor-swizzled). V: 64 d-rows x 64 keys.
    __shared__ __align__(16) unsigned Ks[2][2048];
    __shared__ __align__(16) unsigned Vs[2][2048];

    const int bid  = blockIdx.x;
    const int xcd  = bid & 7;                  // XCD head-pinning (FETCH 104->26 MB, R3)
    const int sIdx = bid >> 3;                 // 0..95
    const int bh   = xcd * 12 + (sIdx % 12);
    const int qt   = sIdx / 12;                // 0..7 (128-row q-tiles)
    const int h    = bh % kH;
    const int t    = threadIdx.x;
    const int wave = t >> 6;
    const int lane = t & 63;
    const int l31  = lane & 31;
    const int hh   = lane >> 5;                // half of the wave

    const float al = alpha[h] * (kScale * kScale);
    const float be = beta[h] * kScale;
    const float ga = gamma[h];

    const float* qp = q + (long)bh * kND;
    const unsigned short* kp = kbf + (long)bh * kND;
    const unsigned short* vp = vtbf + (long)bh * kND;   // [d][n]

    // Q B-frags (B[k=d][n=q]: n=l31, k = s*16 + hh*8 + j), from fp32 global, once
    bf16x8 qbF[4];
    {
        const int qrow = qt * 128 + wave * 32 + l31;
        const float* qsrc = qp + (long)qrow * kD;
#pragma unroll
        for (int s = 0; s < 4; ++s) {
            const float4 f0 = *(const float4*)(qsrc + s * 16 + hh * 8);
            const float4 f1 = *(const float4*)(qsrc + s * 16 + hh * 8 + 4);
            uint4 u;
            u.x = pack2_rne(f0.x, f0.y);
            u.y = pack2_rne(f0.z, f0.w);
            u.z = pack2_rne(f1.x, f1.y);
            u.w = pack2_rne(f1.z, f1.w);
            qbF[s] = __builtin_bit_cast(bf16x8, u);
        }
    }

    f32x16 oacc[2];
#pragma unroll
    for (int db = 0; db < 2; ++db)
#pragma unroll
        for (int r = 0; r < 16; ++r)
            oacc[db][r] = 0.f;
    float dacc[4] = {0.f, 0.f, 0.f, 0.f};

    // staging geometry (R2-proven): wave fills 8-row 1KB segments; granule g holds chunk g^(row&7)
    const int srow8 = lane >> 3;
    const int g8    = lane & 7;
    auto stageKV = [&](int buf, int tile) {
        const int k0 = tile * 64;
#pragma unroll
        for (int c = 0; c < 2; ++c) {
            const int r = (c * 4 + wave) * 8 + srow8;          // 0..63
            gl_lds16(kp + (long)(k0 + r) * kD + (g8 ^ srow8) * 8, &Ks[buf][(c * 4 + wave) * 256]);
            gl_lds16(vp + (long)r * kN + k0 + (g8 ^ srow8) * 8, &Vs[buf][(c * 4 + wave) * 256]);
        }
    };

    stageKV(0, 0);

    for (int tile = 0; tile < 16; ++tile) {
        const int buf = tile & 1;
        __syncthreads();                       // drains vmcnt: this tile's staging done
        if (tile + 1 < 16) stageKV(buf ^ 1, tile + 1);

        const unsigned* Kb = Ks[buf];
        const unsigned* Vb = Vs[buf];

        // ---- S^T = K Q^T : two 32-key blocks; C: col=q=l31, row=key=(r&3)+8*(r>>2)+4*hh ----
        f32x16 st[2];
#pragma unroll
        for (int kb = 0; kb < 2; ++kb)
#pragma unroll
            for (int r = 0; r < 16; ++r)
                st[kb][r] = 0.f;
#pragma unroll
        for (int s = 0; s < 4; ++s) {
            const int g = (s << 1) | hh;       // logical granule of A-frag (8 bf16 of d)
#pragma unroll
            for (int kb = 0; kb < 2; ++kb) {
                const int row = kb * 32 + l31;
                bf16x8 ka = *(const bf16x8*)&Kb[row * 32 + ((g ^ (row & 7)) << 2)];
                st[kb] = MFMA32(ka, qbF[s], st[kb]);
            }
        }

        // ---- poly + ReLU + denom + pack to bf16 uints (all in-lane, q = l31) ----
        unsigned u[2][8];
#pragma unroll
        for (int kb = 0; kb < 2; ++kb) {
#pragma unroll
            for (int p = 0; p < 8; ++p) {
                const float s0 = st[kb][2 * p], s1 = st[kb][2 * p + 1];
                const float w0 = fmaxf(fmaf(fmaf(al, s0, be), s0, ga), 0.f);
                const float w1 = fmaxf(fmaf(fmaf(al, s1, be), s1, ga), 0.f);
                dacc[p & 3] += w0 + w1;
                u[kb][p] = pack2_rhu(w0, w1);
            }
        }

        // ---- cross-half exchange -> PV A-frags (A[q=l31][key=s*16+hh*8+j]) ----
        bf16x8 pa[4];
#pragma unroll
        for (int s = 0; s < 4; ++s) {
            const int kb = s >> 1;
            const int b = (s & 1) * 4;
            const unsigned snd0 = hh ? u[kb][b + 0] : u[kb][b + 2];
            const unsigned snd1 = hh ? u[kb][b + 1] : u[kb][b + 3];
            const unsigned r0 = (unsigned)__shfl_xor((int)snd0, 32);
            const unsigned r1 = (unsigned)__shfl_xor((int)snd1, 32);
            uint4 fr;
            fr.x = hh ? r0 : u[kb][b + 0];
            fr.y = hh ? r1 : u[kb][b + 1];
            fr.z = hh ? u[kb][b + 2] : r0;
            fr.w = hh ? u[kb][b + 3] : r1;
            pa[s] = __builtin_bit_cast(bf16x8, fr);
        }

        // ---- O += P V : A=P, B=V[key][d] from Vt LDS ----
#pragma unroll
        for (int db = 0; db < 2; ++db) {
            const int row = db * 32 + l31;
            const int rb = row * 32;
            const int rsw = row & 7;
#pragma unroll
            for (int s = 0; s < 4; ++s) {
                bf16x8 vb = *(const bf16x8*)&Vb[rb + ((((s << 1) | hh) ^ rsw) << 2)];
                oacc[db] = MFMA32(pa[s], vb, oacc[db]);
            }
        }
    }

    // ---- denominator (q = l31): in-lane sum + cross-half merge ----
    float d = (dacc[0] + dacc[1]) + (dacc[2] + dacc[3]);
    d += __shfl_xor(d, 32);
    const float inv = 1.0f / (d + kEps);

    // ---- store: C row = (r&3)+8*(r>>2)+4*hh, col = db*32+l31 (full 128B lines) ----
    const long obase = (long)bh * kND;
    const int rowbase = qt * 128 + wave * 32;
#pragma unroll
    for (int r = 0; r < 16; ++r) {
        const int row32 = (r & 3) + 8 * (r >> 2) + 4 * hh;
        const float iv = __shfl(inv, row32);   // inv lives at lane q (both halves valid)
        float* o = out + obase + (long)(rowbase + row32) * kD + l31;
        o[0]  = oacc[0][r] * iv;
        o[32] = oacc[1][r] * iv;
    }
}

// ---------- fallback (fp32 direct) for small ws ----------
static constexpr int KSU = 36;
static constexpr int VSU = 36;
static constexpr int PSU = 36;

__global__ __launch_bounds__(256, 3) void l2q_attn_fb(
    const float* __restrict__ q, const float* __restrict__ k, const float* __restrict__ v,
    const float* __restrict__ alpha, const float* __restrict__ beta, const float* __restrict__ gamma,
    float* __restrict__ out)
{
    __shared__ __align__(16) unsigned KsU[64 * KSU];
    __shared__ __align__(16) unsigned VtU[64 * VSU];
    __shared__ __align__(16) unsigned PU[128 * PSU];

    const int bid  = blockIdx.x;
    const int bh   = bid >> 3;
    const int qt   = bid & 7;
    const int h    = bh % kH;
    const int t    = threadIdx.x;
    const int wave = t >> 6;
    const int lane = t & 63;
    const int quad = lane >> 4;
    const int l15  = lane & 15;

    const float al = alpha[h], be = beta[h], ga = gamma[h];

    const long base = (long)bh * kN * kD;
    const float* qp = q + base;
    const float* kp = k + base;
    const float* vp = v + base;

    bf16x8 qa[2][2];
#pragma unroll
    for (int rb = 0; rb < 2; ++rb) {
        const int row = qt * 128 + wave * 32 + rb * 16 + l15;
#pragma unroll
        for (int kc = 0; kc < 2; ++kc) {
            const float* src = qp + (long)row * kD + kc * 32 + quad * 8;
            const float4 f0 = *(const float4*)(src);
            const float4 f1 = *(const float4*)(src + 4);
            uint4 u;
            u.x = pack2_rne(f0.x, f0.y);
            u.y = pack2_rne(f0.z, f0.w);
            u.z = pack2_rne(f1.x, f1.y);
            u.w = pack2_rne(f1.z, f1.w);
            qa[rb][kc] = __builtin_bit_cast(bf16x8, u);
        }
    }

    f32x4 oacc[2][4];
#pragma unroll
    for (int rb = 0; rb < 2; ++rb)
#pragma unroll
        for (int db = 0; db < 4; ++db)
            oacc[rb][db] = (f32x4){0.f, 0.f, 0.f, 0.f};

    float dsum[2][4] = {{0.f, 0.f, 0.f, 0.f}, {0.f, 0.f, 0.f, 0.f}};
    unsigned* Pw = &PU[wave * 32 * PSU];

    for (int tile = 0; tile < 16; ++tile) {
        __syncthreads();
        const int k0 = tile * 64;
#pragma unroll
        for (int r = 0; r < 4; ++r) {
            const int f4 = t + 256 * r;
            const int n = f4 >> 4, d4 = f4 & 15;
            const float4 kg = *(const float4*)(kp + (long)(k0 + n) * kD + 4 * d4);
            uint2 pk;
            pk.x = pack2_rne(kg.x, kg.y);
            pk.y = pack2_rne(kg.z, kg.w);
            *(uint2*)&KsU[n * KSU + 2 * d4] = pk;
        }
#pragma unroll
        for (int r = 0; r < 2; ++r) {
            const int u = t + 256 * r;
            const int key2 = u & 31, d4 = u >> 5;
            const float* s0 = vp + (long)(k0 + 2 * key2) * kD + 4 * d4;
            const float4 va = *(const float4*)(s0);
            const float4 vb = *(const float4*)(s0 + kD);
            VtU[(4 * d4 + 0) * VSU + key2] = pack2_rne(va.x, vb.x);
            VtU[(4 * d4 + 1) * VSU + key2] = pack2_rne(va.y, vb.y);
            VtU[(4 * d4 + 2) * VSU + key2] = pack2_rne(va.z, vb.z);
            VtU[(4 * d4 + 3) * VSU + key2] = pack2_rne(va.w, vb.w);
        }
        __syncthreads();

        f32x4 s[2][4];
#pragma unroll
        for (int rb = 0; rb < 2; ++rb)
#pragma unroll
            for (int nb = 0; nb < 4; ++nb)
                s[rb][nb] = (f32x4){0.f, 0.f, 0.f, 0.f};
#pragma unroll
        for (int nb = 0; nb < 4; ++nb) {
            bf16x8 kb0 = *(const bf16x8*)&KsU[(nb * 16 + l15) * KSU + 4 * quad];
            bf16x8 kb1 = *(const bf16x8*)&KsU[(nb * 16 + l15) * KSU + 16 + 4 * quad];
#pragma unroll
            for (int rb = 0; rb < 2; ++rb) {
                s[rb][nb] = MFMA16(qa[rb][0], kb0, s[rb][nb]);
                s[rb][nb] = MFMA16(qa[rb][1], kb1, s[rb][nb]);
            }
        }

        const bool ev = (lane & 1) == 0;
#pragma unroll
        for (int rb = 0; rb < 2; ++rb) {
#pragma unroll
            for (int nb = 0; nb < 4; ++nb) {
                float w0, w1, w2, w3;
                {
                    float l0 = s[rb][nb][0] * kScale;
                    float l1 = s[rb][nb][1] * kScale;
                    float l2 = s[rb][nb][2] * kScale;
                    float l3 = s[rb][nb][3] * kScale;
                    w0 = fmaxf(fmaf(fmaf(al, l0, be), l0, ga), 0.f);
                    w1 = fmaxf(fmaf(fmaf(al, l1, be), l1, ga), 0.f);
                    w2 = fmaxf(fmaf(fmaf(al, l2, be), l2, ga), 0.f);
                    w3 = fmaxf(fmaf(fmaf(al, l3, be), l3, ga), 0.f);
                }
                dsum[rb][0] += w0; dsum[rb][1] += w1;
                dsum[rb][2] += w2; dsum[rb][3] += w3;

                const float o0 = __shfl_xor(w0, 1);
                const float o1 = __shfl_xor(w1, 1);
                const float o2 = __shfl_xor(w2, 1);
                const float o3 = __shfl_xor(w3, 1);
                const unsigned pa = ev ? pack2_rne(w0, o0) : pack2_rne(o2, w2);
                const unsigned pb = ev ? pack2_rne(w1, o1) : pack2_rne(o3, w3);
                const int r0 = ev ? 0 : 2;
                const int cu = (16 * nb + (l15 & ~1)) >> 1;
                const int rowb = rb * 16 + quad * 4 + r0;
                Pw[rowb * PSU + cu] = pa;
                Pw[(rowb + 1) * PSU + cu] = pb;
            }
        }

        bf16x8 pf[2][2];
#pragma unroll
        for (int rb = 0; rb < 2; ++rb)
#pragma unroll
            for (int kc = 0; kc < 2; ++kc)
                pf[rb][kc] = *(const bf16x8*)&Pw[(rb * 16 + l15) * PSU + 16 * kc + 4 * quad];
#pragma unroll
        for (int db = 0; db < 4; ++db) {
            bf16x8 vf0 = *(const bf16x8*)&VtU[(db * 16 + l15) * VSU + 4 * quad];
            bf16x8 vf1 = *(const bf16x8*)&VtU[(db * 16 + l15) * VSU + 16 + 4 * quad];
#pragma unroll
            for (int rb = 0; rb < 2; ++rb) {
                oacc[rb][db] = MFMA16(pf[rb][0], vf0, oacc[rb][db]);
                oacc[rb][db] = MFMA16(pf[rb][1], vf1, oacc[rb][db]);
            }
        }
    }

#pragma unroll
    for (int rb = 0; rb < 2; ++rb)
#pragma unroll
        for (int i = 0; i < 4; ++i) {
            float d = dsum[rb][i];
            d += __shfl_xor(d, 1);
            d += __shfl_xor(d, 2);
            d += __shfl_xor(d, 4);
            d += __shfl_xor(d, 8);
            dsum[rb][i] = 1.0f / (d + kEps);
        }

#pragma unroll
    for (int rb = 0; rb < 2; ++rb)
#pragma unroll
        for (int db = 0; db < 4; ++db)
#pragma unroll
            for (int i = 0; i < 4; ++i) {
                const int row = qt * 128 + wave * 32 + rb * 16 + quad * 4 + i;
                out[base + (long)row * kD + db * 16 + l15] = oacc[rb][db][i] * dsum[rb][i];
            }
}

extern "C" void kernel_launch(void* const* d_in, const int* in_sizes, int n_in,
                              void* d_out, int out_size, void* d_ws, size_t ws_size,
                              hipStream_t stream) {
    const float* q     = (const float*)d_in[0];
    const float* k     = (const float*)d_in[1];
    const float* v     = (const float*)d_in[2];
    const float* alpha = (const float*)d_in[3];
    const float* beta  = (const float*)d_in[4];
    const float* gamma = (const float*)d_in[5];
    float* out = (float*)d_out;

    if (ws_size < (size_t)kWsNeeded) {
        l2q_attn_fb<<<dim3(768), dim3(256), 0, stream>>>(q, k, v, alpha, beta, gamma, out);
        return;
    }

    unsigned* kbf = (unsigned*)d_ws;
    unsigned* vtb = kbf + kTensorElems / 2;

    prep<<<dim3(1536), dim3(256), 0, stream>>>(k, v, kbf, vtb);
    l2q_main<<<dim3(768), dim3(256), 0, stream>>>(
        q, (const unsigned short*)kbf, (const unsigned short*)vtb,
        alpha, beta, gamma, out);
}

// Round 6
// 146.425 us; speedup vs baseline: 1.2875x; 1.0310x over previous
//
#include <hip/hip_runtime.h>
#include <hip/hip_bf16.h>

typedef __attribute__((ext_vector_type(8))) short bf16x8;
typedef __attribute__((ext_vector_type(4))) float f32x4;
typedef __attribute__((ext_vector_type(16))) float f32x16;

#define MFMA16(a, b, c) __builtin_amdgcn_mfma_f32_16x16x32_bf16(a, b, c, 0, 0, 0)
#define MFMA32(a, b, c) __builtin_amdgcn_mfma_f32_32x32x16_bf16(a, b, c, 0, 0, 0)

static constexpr int kH = 12;
static constexpr int kN = 1024;
static constexpr int kD = 64;
static constexpr int kBH = 96;
static constexpr int kND = kN * kD;            // 65536 per head
static constexpr float kScale = 0.125f;
static constexpr float kEps = 1e-6f;
static constexpr long kTensorElems = (long)kBH * kND;     // 6291456
static constexpr long kWsNeeded = 2 * kTensorElems * 2;   // K + Vt bf16

// ---------- bf16 helpers ----------
__device__ __forceinline__ unsigned bfbits(float x) {
    union { __hip_bfloat16 h; unsigned short u; } c;
    c.h = __float2bfloat16(x);
    return (unsigned)c.u;
}
__device__ __forceinline__ unsigned pack2_rne(float a, float b) {
    return bfbits(a) | (bfbits(b) << 16);
}
// round-half-up pack (operands >= 0 post-ReLU)
__device__ __forceinline__ unsigned pack2_rhu(float lo, float hi) {
    unsigned a = __builtin_bit_cast(unsigned, lo) + 0x8000u;
    unsigned b = __builtin_bit_cast(unsigned, hi) + 0x8000u;
    return __builtin_amdgcn_perm(b, a, 0x07060302u);
}
__device__ __forceinline__ void gl_lds16(const void* g, void* l) {
    __builtin_amdgcn_global_load_lds(
        (const __attribute__((address_space(1))) void*)g,
        (__attribute__((address_space(3))) void*)l, 16, 0, 0);
}

// ---------- prepass: K fp32->bf16 cast + V fp32 [n][d] -> Vt bf16 [d][key-permuted n] ----
// Vt key positions are stored with key bits 2<->3 swapped (kappa involution) so the
// main kernel's PV A-fragments need NO cross-lane exchange (key-permutation-invariant sum).
__global__ __launch_bounds__(256, 2) void prep(
    const float* __restrict__ k, const float* __restrict__ v,
    unsigned* __restrict__ kbf, unsigned* __restrict__ vtb)
{
    static constexpr int TS = 68;
    __shared__ float T32[64 * TS];
    const int bid = blockIdx.x;                   // 1536 = 96 bh * 16 nt
    const int bh = bid >> 4, nt = bid & 15;
    const int t = threadIdx.x;

    const float* kp = k + (long)bh * kND + (long)nt * 64 * kD;
    unsigned* ko = kbf + ((long)bh * kND + (long)nt * 64 * kD) / 2;
#pragma unroll
    for (int r = 0; r < 4; ++r) {
        const int f4 = t + 256 * r;
        const float4 f = ((const float4*)kp)[f4];
        uint2 u;
        u.x = pack2_rne(f.x, f.y);
        u.y = pack2_rne(f.z, f.w);
        *(uint2*)&ko[f4 * 2] = u;
    }

    const float* vp = v + (long)bh * kND + (long)nt * 64 * kD;
#pragma unroll
    for (int r = 0; r < 4; ++r) {
        const int f4 = t + 256 * r;
        const int n = f4 >> 4, d4 = f4 & 15;
        const float4 f = *(const float4*)(vp + (long)n * kD + 4 * d4);
        *(float4*)&T32[n * TS + 4 * d4] = f;
    }
    __syncthreads();
    const int d = t >> 2, c = t & 3;
    unsigned u[8];
#pragma unroll
    for (int j = 0; j < 8; ++j) {
        const int key = c * 16 + 2 * j;
        u[j] = pack2_rne(T32[key * TS + d], T32[(key + 1) * TS + d]);
    }
    unsigned* dst = vtb + (long)bh * (kND / 2) + (long)d * (kN / 2) + nt * 32 + c * 8;
    // key bit2<->bit3 swap permutation: uint cols {0,1,2,3} <- {u0,u1,u4,u5},
    // cols {4,5,6,7} <- {u2,u3,u6,u7}
    uint4 A, B;
    A.x = u[0]; A.y = u[1]; A.z = u[4]; A.w = u[5];
    B.x = u[2]; B.y = u[3]; B.z = u[6]; B.w = u[7];
    *(uint4*)(dst)     = A;
    *(uint4*)(dst + 4) = B;
}

// ---------- main attention kernel: 32x32x16 MFMA, permuted-V, no exchange ----------
// grid 768: 128 q-rows/block, 4 waves x 32 q-rows. 64-key dbuf tiles, 1 barrier/tile.
__global__ __launch_bounds__(256, 3) void l2q_main(
    const float* __restrict__ q,
    const unsigned short* __restrict__ kbf, const unsigned short* __restrict__ vtbf,
    const float* __restrict__ alpha, const float* __restrict__ beta, const float* __restrict__ gamma,
    float* __restrict__ out)
{
    // K: 64 key-rows x 64 bf16 (32 uints, 8 granules/row, xor-swizzled). V: 64 d-rows x 64 keys.
    __shared__ __align__(16) unsigned Ks[2][2048];
    __shared__ __align__(16) unsigned Vs[2][2048];

    const int bid  = blockIdx.x;
    const int xcd  = bid & 7;                  // XCD head-pinning (FETCH 104->26 MB, R3)
    const int sIdx = bid >> 3;                 // 0..95
    const int bh   = xcd * 12 + (sIdx % 12);
    const int qt   = sIdx / 12;                // 0..7 (128-row q-tiles)
    const int h    = bh % kH;
    const int t    = threadIdx.x;
    const int wave = t >> 6;
    const int lane = t & 63;
    const int l31  = lane & 31;
    const int hh   = lane >> 5;                // half of the wave

    const float al = alpha[h] * (kScale * kScale);
    const float be = beta[h] * kScale;
    const float ga = gamma[h];

    const float* qp = q + (long)bh * kND;
    const unsigned short* kp = kbf + (long)bh * kND;
    const unsigned short* vp = vtbf + (long)bh * kND;   // [d][key-permuted n]

    // Q B-frags (B[k=d][n=q]: n=l31, k = s*16 + hh*8 + j), from fp32 global, once
    bf16x8 qbF[4];
    {
        const int qrow = qt * 128 + wave * 32 + l31;
        const float* qsrc = qp + (long)qrow * kD;
#pragma unroll
        for (int s = 0; s < 4; ++s) {
            const float4 f0 = *(const float4*)(qsrc + s * 16 + hh * 8);
            const float4 f1 = *(const float4*)(qsrc + s * 16 + hh * 8 + 4);
            uint4 u;
            u.x = pack2_rne(f0.x, f0.y);
            u.y = pack2_rne(f0.z, f0.w);
            u.z = pack2_rne(f1.x, f1.y);
            u.w = pack2_rne(f1.z, f1.w);
            qbF[s] = __builtin_bit_cast(bf16x8, u);
        }
    }

    f32x16 oacc[2];
#pragma unroll
    for (int db = 0; db < 2; ++db)
#pragma unroll
        for (int r = 0; r < 16; ++r)
            oacc[db][r] = 0.f;
    float dacc[4] = {0.f, 0.f, 0.f, 0.f};

    // staging geometry (R2-proven): wave fills 8-row 1KB segments; granule g holds chunk g^(row&7)
    const int srow8 = lane >> 3;
    const int g8    = lane & 7;
    auto stageKV = [&](int buf, int tile) {
        const int k0 = tile * 64;
#pragma unroll
        for (int c = 0; c < 2; ++c) {
            const int r = (c * 4 + wave) * 8 + srow8;          // 0..63
            gl_lds16(kp + (long)(k0 + r) * kD + (g8 ^ srow8) * 8, &Ks[buf][(c * 4 + wave) * 256]);
            gl_lds16(vp + (long)r * kN + k0 + (g8 ^ srow8) * 8, &Vs[buf][(c * 4 + wave) * 256]);
        }
    };

    stageKV(0, 0);

    for (int tile = 0; tile < 16; ++tile) {
        const int buf = tile & 1;
        __syncthreads();                       // drains vmcnt: this tile's staging done
        if (tile + 1 < 16) stageKV(buf ^ 1, tile + 1);

        const unsigned* Kb = Ks[buf];
        const unsigned* Vb = Vs[buf];

        // ---- S^T = K Q^T : two 32-key blocks; C: col=q=l31, row=key=(r&3)+8*(r>>2)+4*hh ----
        f32x16 st[2];
#pragma unroll
        for (int kb = 0; kb < 2; ++kb)
#pragma unroll
            for (int r = 0; r < 16; ++r)
                st[kb][r] = 0.f;
#pragma unroll
        for (int s = 0; s < 4; ++s) {
            const int g = (s << 1) | hh;       // logical granule of A-frag (8 bf16 of d)
#pragma unroll
            for (int kb = 0; kb < 2; ++kb) {
                const int row = kb * 32 + l31;
                bf16x8 ka = *(const bf16x8*)&Kb[row * 32 + ((g ^ (row & 7)) << 2)];
                st[kb] = MFMA32(ka, qbF[s], st[kb]);
            }
        }

        // ---- hoist V-frag loads (independent of S; overlap DS latency with poly VALU) ----
        bf16x8 vfr[2][4];
#pragma unroll
        for (int db = 0; db < 2; ++db) {
            const int row = db * 32 + l31;
            const int rb = row * 32;
            const int rsw = row & 7;
#pragma unroll
            for (int s = 0; s < 4; ++s)
                vfr[db][s] = *(const bf16x8*)&Vb[rb + ((((s << 1) | hh) ^ rsw) << 2)];
        }

        // ---- poly + ReLU + denom + pack to bf16 uints (all in-lane, q = l31) ----
        unsigned u[2][8];
#pragma unroll
        for (int kb = 0; kb < 2; ++kb) {
#pragma unroll
            for (int p = 0; p < 8; ++p) {
                const float s0 = st[kb][2 * p], s1 = st[kb][2 * p + 1];
                const float w0 = fmaxf(fmaf(fmaf(al, s0, be), s0, ga), 0.f);
                const float w1 = fmaxf(fmaf(fmaf(al, s1, be), s1, ga), 0.f);
                dacc[p & 3] += w0 + w1;
                u[kb][p] = pack2_rhu(w0, w1);
            }
        }

        // ---- O += P V : A-frag s = u[s>>1][4*(s&1)..+3] directly (kappa-permuted keys
        //      match the kappa-permuted Vt layout; no cross-lane exchange needed) ----
#pragma unroll
        for (int s = 0; s < 4; ++s) {
            uint4 fr;
            const int kb = s >> 1, b = (s & 1) * 4;
            fr.x = u[kb][b + 0];
            fr.y = u[kb][b + 1];
            fr.z = u[kb][b + 2];
            fr.w = u[kb][b + 3];
            const bf16x8 pa = __builtin_bit_cast(bf16x8, fr);
            oacc[0] = MFMA32(pa, vfr[0][s], oacc[0]);
            oacc[1] = MFMA32(pa, vfr[1][s], oacc[1]);
        }
    }

    // ---- denominator (q = l31): in-lane sum + cross-half merge ----
    float d = (dacc[0] + dacc[1]) + (dacc[2] + dacc[3]);
    d += __shfl_xor(d, 32);
    const float inv = 1.0f / (d + kEps);

    // ---- store: C row = (r&3)+8*(r>>2)+4*hh, col = db*32+l31 (full 128B lines) ----
    const long obase = (long)bh * kND;
    const int rowbase = qt * 128 + wave * 32;
#pragma unroll
    for (int r = 0; r < 16; ++r) {
        const int row32 = (r & 3) + 8 * (r >> 2) + 4 * hh;
        const float iv = __shfl(inv, row32);   // inv lives at lane q (both halves valid)
        float* o = out + obase + (long)(rowbase + row32) * kD + l31;
        o[0]  = oacc[0][r] * iv;
        o[32] = oacc[1][r] * iv;
    }
}

// ---------- fallback (fp32 direct) for small ws ----------
static constexpr int KSU = 36;
static constexpr int VSU = 36;
static constexpr int PSU = 36;

__global__ __launch_bounds__(256, 3) void l2q_attn_fb(
    const float* __restrict__ q, const float* __restrict__ k, const float* __restrict__ v,
    const float* __restrict__ alpha, const float* __restrict__ beta, const float* __restrict__ gamma,
    float* __restrict__ out)
{
    __shared__ __align__(16) unsigned KsU[64 * KSU];
    __shared__ __align__(16) unsigned VtU[64 * VSU];
    __shared__ __align__(16) unsigned PU[128 * PSU];

    const int bid  = blockIdx.x;
    const int bh   = bid >> 3;
    const int qt   = bid & 7;
    const int h    = bh % kH;
    const int t    = threadIdx.x;
    const int wave = t >> 6;
    const int lane = t & 63;
    const int quad = lane >> 4;
    const int l15  = lane & 15;

    const float al = alpha[h], be = beta[h], ga = gamma[h];

    const long base = (long)bh * kN * kD;
    const float* qp = q + base;
    const float* kp = k + base;
    const float* vp = v + base;

    bf16x8 qa[2][2];
#pragma unroll
    for (int rb = 0; rb < 2; ++rb) {
        const int row = qt * 128 + wave * 32 + rb * 16 + l15;
#pragma unroll
        for (int kc = 0; kc < 2; ++kc) {
            const float* src = qp + (long)row * kD + kc * 32 + quad * 8;
            const float4 f0 = *(const float4*)(src);
            const float4 f1 = *(const float4*)(src + 4);
            uint4 u;
            u.x = pack2_rne(f0.x, f0.y);
            u.y = pack2_rne(f0.z, f0.w);
            u.z = pack2_rne(f1.x, f1.y);
            u.w = pack2_rne(f1.z, f1.w);
            qa[rb][kc] = __builtin_bit_cast(bf16x8, u);
        }
    }

    f32x4 oacc[2][4];
#pragma unroll
    for (int rb = 0; rb < 2; ++rb)
#pragma unroll
        for (int db = 0; db < 4; ++db)
            oacc[rb][db] = (f32x4){0.f, 0.f, 0.f, 0.f};

    float dsum[2][4] = {{0.f, 0.f, 0.f, 0.f}, {0.f, 0.f, 0.f, 0.f}};
    unsigned* Pw = &PU[wave * 32 * PSU];

    for (int tile = 0; tile < 16; ++tile) {
        __syncthreads();
        const int k0 = tile * 64;
#pragma unroll
        for (int r = 0; r < 4; ++r) {
            const int f4 = t + 256 * r;
            const int n = f4 >> 4, d4 = f4 & 15;
            const float4 kg = *(const float4*)(kp + (long)(k0 + n) * kD + 4 * d4);
            uint2 pk;
            pk.x = pack2_rne(kg.x, kg.y);
            pk.y = pack2_rne(kg.z, kg.w);
            *(uint2*)&KsU[n * KSU + 2 * d4] = pk;
        }
#pragma unroll
        for (int r = 0; r < 2; ++r) {
            const int u = t + 256 * r;
            const int key2 = u & 31, d4 = u >> 5;
            const float* s0 = vp + (long)(k0 + 2 * key2) * kD + 4 * d4;
            const float4 va = *(const float4*)(s0);
            const float4 vb = *(const float4*)(s0 + kD);
            VtU[(4 * d4 + 0) * VSU + key2] = pack2_rne(va.x, vb.x);
            VtU[(4 * d4 + 1) * VSU + key2] = pack2_rne(va.y, vb.y);
            VtU[(4 * d4 + 2) * VSU + key2] = pack2_rne(va.z, vb.z);
            VtU[(4 * d4 + 3) * VSU + key2] = pack2_rne(va.w, vb.w);
        }
        __syncthreads();

        f32x4 s[2][4];
#pragma unroll
        for (int rb = 0; rb < 2; ++rb)
#pragma unroll
            for (int nb = 0; nb < 4; ++nb)
                s[rb][nb] = (f32x4){0.f, 0.f, 0.f, 0.f};
#pragma unroll
        for (int nb = 0; nb < 4; ++nb) {
            bf16x8 kb0 = *(const bf16x8*)&KsU[(nb * 16 + l15) * KSU + 4 * quad];
            bf16x8 kb1 = *(const bf16x8*)&KsU[(nb * 16 + l15) * KSU + 16 + 4 * quad];
#pragma unroll
            for (int rb = 0; rb < 2; ++rb) {
                s[rb][nb] = MFMA16(qa[rb][0], kb0, s[rb][nb]);
                s[rb][nb] = MFMA16(qa[rb][1], kb1, s[rb][nb]);
            }
        }

        const bool ev = (lane & 1) == 0;
#pragma unroll
        for (int rb = 0; rb < 2; ++rb) {
#pragma unroll
            for (int nb = 0; nb < 4; ++nb) {
                float w0, w1, w2, w3;
                {
                    float l0 = s[rb][nb][0] * kScale;
                    float l1 = s[rb][nb][1] * kScale;
                    float l2 = s[rb][nb][2] * kScale;
                    float l3 = s[rb][nb][3] * kScale;
                    w0 = fmaxf(fmaf(fmaf(al, l0, be), l0, ga), 0.f);
                    w1 = fmaxf(fmaf(fmaf(al, l1, be), l1, ga), 0.f);
                    w2 = fmaxf(fmaf(fmaf(al, l2, be), l2, ga), 0.f);
                    w3 = fmaxf(fmaf(fmaf(al, l3, be), l3, ga), 0.f);
                }
                dsum[rb][0] += w0; dsum[rb][1] += w1;
                dsum[rb][2] += w2; dsum[rb][3] += w3;

                const float o0 = __shfl_xor(w0, 1);
                const float o1 = __shfl_xor(w1, 1);
                const float o2 = __shfl_xor(w2, 1);
                const float o3 = __shfl_xor(w3, 1);
                const unsigned pa = ev ? pack2_rne(w0, o0) : pack2_rne(o2, w2);
                const unsigned pb = ev ? pack2_rne(w1, o1) : pack2_rne(o3, w3);
                const int r0 = ev ? 0 : 2;
                const int cu = (16 * nb + (l15 & ~1)) >> 1;
                const int rowb = rb * 16 + quad * 4 + r0;
                Pw[rowb * PSU + cu] = pa;
                Pw[(rowb + 1) * PSU + cu] = pb;
            }
        }

        bf16x8 pf[2][2];
#pragma unroll
        for (int rb = 0; rb < 2; ++rb)
#pragma unroll
            for (int kc = 0; kc < 2; ++kc)
                pf[rb][kc] = *(const bf16x8*)&Pw[(rb * 16 + l15) * PSU + 16 * kc + 4 * quad];
#pragma unroll
        for (int db = 0; db < 4; ++db) {
            bf16x8 vf0 = *(const bf16x8*)&VtU[(db * 16 + l15) * VSU + 4 * quad];
            bf16x8 vf1 = *(const bf16x8*)&VtU[(db * 16 + l15) * VSU + 16 + 4 * quad];
#pragma unroll
            for (int rb = 0; rb < 2; ++rb) {
                oacc[rb][db] = MFMA16(pf[rb][0], vf0, oacc[rb][db]);
                oacc[rb][db] = MFMA16(pf[rb][1], vf1, oacc[rb][db]);
            }
        }
    }

#pragma unroll
    for (int rb = 0; rb < 2; ++rb)
#pragma unroll
        for (int i = 0; i < 4; ++i) {
            float d = dsum[rb][i];
            d += __shfl_xor(d, 1);
            d += __shfl_xor(d, 2);
            d += __shfl_xor(d, 4);
            d += __shfl_xor(d, 8);
            dsum[rb][i] = 1.0f / (d + kEps);
        }

#pragma unroll
    for (int rb = 0; rb < 2; ++rb)
#pragma unroll
        for (int db = 0; db < 4; ++db)
#pragma unroll
            for (int i = 0; i < 4; ++i) {
                const int row = qt * 128 + wave * 32 + rb * 16 + quad * 4 + i;
                out[base + (long)row * kD + db * 16 + l15] = oacc[rb][db][i] * dsum[rb][i];
            }
}

extern "C" void kernel_launch(void* const* d_in, const int* in_sizes, int n_in,
                              void* d_out, int out_size, void* d_ws, size_t ws_size,
                              hipStream_t stream) {
    const float* q     = (const float*)d_in[0];
    const float* k     = (const float*)d_in[1];
    const float* v     = (const float*)d_in[2];
    const float* alpha = (const float*)d_in[3];
    const float* beta  = (const float*)d_in[4];
    const float* gamma = (const float*)d_in[5];
    float* out = (float*)d_out;

    if (ws_size < (size_t)kWsNeeded) {
        l2q_attn_fb<<<dim3(768), dim3(256), 0, stream>>>(q, k, v, alpha, beta, gamma, out);
        return;
    }

    unsigned* kbf = (unsigned*)d_ws;
    unsigned* vtb = kbf + kTensorElems / 2;

    prep<<<dim3(1536), dim3(256), 0, stream>>>(k, v, kbf, vtb);
    l2q_main<<<dim3(768), dim3(256), 0, stream>>>(
        q, (const unsigned short*)kbf, (const unsigned short*)vtb,
        alpha, beta, gamma, out);
}